// Round 10
// baseline (328.229 us; speedup 1.0000x reference)
//
#include <hip/hip_runtime.h>

#define D_DIM 256
#define K_CODES 1024
#define HW 4096                  // H*W
#define BDHW 33554432            // 32*256*64*64
#define N_POS 131072             // 32*64*64
#define TAU 0.25f                // ~14 sigma of f16 pair-error
#define SKIPD 33                 // out0/out1 scratch region: b==0, d<33

typedef __attribute__((ext_vector_type(8))) _Float16 half8v;
typedef __attribute__((ext_vector_type(4))) float float4v;

__device__ __forceinline__ void load_lds16(const void* g, void* l) {
    __builtin_amdgcn_global_load_lds(
        (const __attribute__((address_space(1))) unsigned int*)g,
        (__attribute__((address_space(3))) unsigned int*)l, 16, 0, 0);
}

// ---------------------------------------------------------------------------
// Kernel 1a: pre-swizzled f16 embT (same as benched round-6 version).
// ---------------------------------------------------------------------------
__global__ void vq_prep(const float* __restrict__ embed, uint4* __restrict__ embT) {
    const int c  = blockIdx.x;                   // 64 chunks
    const int nc = c >> 3, dc = c & 7;
    const int t  = threadIdx.x;
#pragma unroll
    for (int i = 0; i < 2; ++i) {
        int p  = i * 256 + t;                    // piece 0..511 (16B each)
        int r  = p >> 2, sp = p & 3;
        int s  = sp ^ ((r >> 1) & 3);
        int k  = nc * 128 + r;
        int db = dc * 32 + s * 8;
        union { _Float16 h[8]; uint4 u; } pk;
#pragma unroll
        for (int j = 0; j < 8; ++j)
            pk.h[j] = (_Float16)embed[(size_t)(db + j) * K_CODES + k];
        embT[c * 512 + p] = pk.u;
    }
}

// ---------------------------------------------------------------------------
// Kernel 1b: enorm + zero refine counter (unchanged).
// ---------------------------------------------------------------------------
__global__ void vq_enorm(const float* __restrict__ embed,
                         float* __restrict__ enorm, int* __restrict__ count) {
    __shared__ float part[256];
    const int t = threadIdx.x;
    const int k = blockIdx.x * 128 + (t & 127);
    const int hf = t >> 7;
    float s = 0.f;
#pragma unroll 4
    for (int d = hf * 128; d < hf * 128 + 128; ++d) {
        float e = embed[(size_t)d * K_CODES + k];
        s = fmaf(e, e, s);
    }
    part[t] = s;
    __syncthreads();
    if (t < 128) enorm[k] = part[t] + part[t + 128];
    if (blockIdx.x == 0 && t == 0) *count = 0;
}

// ---------------------------------------------------------------------------
// Kernel 2: f16 MFMA distances + argmin — main loop IDENTICAL to the 251-us
// round-6 version (ring-4 8KB, stage-ahead-2, vmcnt(4), aR[4][4] d<128,
// A-LDS 32KB d>=128). NEW: fused gather epilogue — the block writes its own
// 128 positions' quantize columns to out0/out1 (256 KB, coalesced 512B),
// skipping the b==0,d<33 scratch region (vq_cleanup covers it).
// ---------------------------------------------------------------------------
__launch_bounds__(256, 2)
__global__ void vq_argmin(const float* __restrict__ input,
                          const char* __restrict__ embT,
                          const float* __restrict__ embed,
                          const float* __restrict__ enorm,
                          float* __restrict__ indf,
                          float* __restrict__ out0,
                          float* __restrict__ out1,
                          int* __restrict__ count,
                          int* __restrict__ list) {
    __shared__ __align__(16) char lds[69632];
    char*  Als = lds;                            // 32 KB: row r<128 -> 256B, 16 slots, d=128+slot*8+j
    char*  Bls = lds + 32768;                    // 4 x 8 KB B ring
    float* Els = (float*)(lds + 65536);          // 4 KB enorm

    const int t    = threadIdx.x;
    const int lane = t & 63;
    const int wid  = t >> 6;
    const int blk  = blockIdx.x;                 // 1024 blocks
    const int n0   = blk * 128;
    const int b    = n0 >> 12;
    const int h0   = (n0 & 4095) >> 6;           // rows h0, h0+1
    const int wm = wid >> 1, wn = wid & 1;
    const int l15 = lane & 15, l4 = lane >> 4;

    const char* embTw = embT + wid * 2048 + lane * 16;   // per-wave stage base

    // ---- prologue: stage chunks 0,1 into ring slots 0,1
    load_lds16(embTw,                   Bls + wid * 2048);
    load_lds16(embTw + 1024,            Bls + wid * 2048 + 1024);
    load_lds16(embTw + 8192,            Bls + 8192 + wid * 2048);
    load_lds16(embTw + 8192 + 1024,     Bls + 8192 + wid * 2048 + 1024);

    // ---- stage enorm to LDS
    *reinterpret_cast<float4*>(Els + t * 4) =
        *reinterpret_cast<const float4*>(enorm + t * 4);

    // ---- stage A d in [128,256) to LDS (coalesced dword loads, b128 writes)
    const float* xbase = input + (size_t)b * (D_DIM * HW) + h0 * 64;
#pragma unroll
    for (int half = 0; half < 2; ++half) {
        const int r = half * 64 + lane;
        const float* hp = xbase + half * 64 + lane;
        const int r7 = lane & 7;
#pragma unroll
        for (int q = 0; q < 4; ++q) {
            const int slot = wid * 4 + q;         // 0..15
            const int d = 128 + slot * 8;
            float v[8];
#pragma unroll
            for (int j = 0; j < 8; ++j) v[j] = hp[(size_t)(d + j) * HW];
            union { _Float16 h[8]; uint4 u; } pk;
#pragma unroll
            for (int j = 0; j < 8; ++j) pk.h[j] = (_Float16)v[j];
            const int byte = r * 256 + (((slot & 8) | ((slot & 7) ^ r7)) << 4);
            *reinterpret_cast<uint4*>(Als + byte) = pk.u;
        }
    }

    // ---- A d<128 directly global -> registers (this wave's 64 pos)
    half8v aR[4][4];                             // [mi][dcq], d = dcq*32 + l4*8 + j
    {
        const float* xw = xbase + wm * 64;
#pragma unroll
        for (int dcq = 0; dcq < 4; ++dcq)
#pragma unroll
            for (int mi = 0; mi < 4; ++mi) {
                const float* p = xw + (size_t)(dcq * 32 + l4 * 8) * HW + mi * 16 + l15;
                float v[8];
#pragma unroll
                for (int j = 0; j < 8; ++j) v[j] = p[(size_t)j * HW];
                union { _Float16 h[8]; half8v hv; } pk;
#pragma unroll
                for (int j = 0; j < 8; ++j) pk.h[j] = (_Float16)v[j];
                aR[mi][dcq] = pk.hv;
            }
    }

    asm volatile("s_waitcnt vmcnt(0) lgkmcnt(0)" ::: "memory");
    __builtin_amdgcn_s_barrier();
    __builtin_amdgcn_sched_barrier(0);

    // fragment base addresses
    const int r7a = l15 & 7;
    const int A0 = (wm * 64 + l15) * 256;                      // + mi*4096 + swz
    const int B0 = wn * 4096 + l15 * 64 + ((l4 ^ ((l15 >> 1) & 3)) << 4); // + ni*1024

    float m1[4][4], m2[4][4];
    int   i1[4][4];
#pragma unroll
    for (int mi = 0; mi < 4; ++mi)
#pragma unroll
        for (int r = 0; r < 4; ++r) { m1[mi][r] = 3.402823466e38f; m2[mi][r] = 3.402823466e38f; i1[mi][r] = 0; }

    float4v acc[4][4];

    for (int ss = 0; ss < 8; ++ss) {             // 8 nc chunks of 128 codes
#pragma unroll
        for (int dc = 0; dc < 8; ++dc) {         // K=32 steps (compile-time dc)
            const int s = ss * 8 + dc;
            // 1. stage chunk s+2 into ring slot (dc+2)&3
            if (ss < 7 || dc < 6) {
                const char* src = embTw + (size_t)(s + 2) * 8192;
                char* dst = Bls + ((dc + 2) & 3) * 8192 + wid * 2048;
                load_lds16(src, dst);
                load_lds16(src + 1024, dst + 1024);
            }
            // 2. counted wait
            if (ss < 7 || dc < 6)  asm volatile("s_waitcnt vmcnt(4)" ::: "memory");
            else if (dc == 6)      asm volatile("s_waitcnt vmcnt(2)" ::: "memory");
            else                   asm volatile("s_waitcnt vmcnt(0)" ::: "memory");
            // 3. one barrier per step
            __builtin_amdgcn_s_barrier();
            __builtin_amdgcn_sched_barrier(0);
            // 4. zero acc at chunk start
            if (dc == 0) {
#pragma unroll
                for (int mi = 0; mi < 4; ++mi)
#pragma unroll
                    for (int ni = 0; ni < 4; ++ni) acc[mi][ni] = (float4v){0.f, 0.f, 0.f, 0.f};
            }
            // 5. fragments
            const char* curB = Bls + (dc & 3) * 8192;
            half8v bF[4], aU[4];
#pragma unroll
            for (int ni = 0; ni < 4; ++ni)
                bF[ni] = *reinterpret_cast<const half8v*>(curB + B0 + ni * 1024);
            if (dc < 4) {
#pragma unroll
                for (int mi = 0; mi < 4; ++mi) aU[mi] = aR[mi][dc];
            } else {
                const int slot = (dc - 4) * 4 + l4;
                const int swz = ((slot & 8) | ((slot & 7) ^ r7a)) << 4;
#pragma unroll
                for (int mi = 0; mi < 4; ++mi)
                    aU[mi] = *reinterpret_cast<const half8v*>(Als + A0 + mi * 4096 + swz);
            }
            // 6. MFMA
            __builtin_amdgcn_s_setprio(1);
#pragma unroll
            for (int mi = 0; mi < 4; ++mi)
#pragma unroll
                for (int ni = 0; ni < 4; ++ni)
                    acc[mi][ni] = __builtin_amdgcn_mfma_f32_16x16x32_f16(aU[mi], bF[ni], acc[mi][ni], 0, 0, 0);
            __builtin_amdgcn_s_setprio(0);
            // 7. epilogue per 128-code chunk
            if (dc == 7) {
#pragma unroll
                for (int ni = 0; ni < 4; ++ni) {
                    int code = ss * 128 + wn * 64 + ni * 16 + l15;
                    float en = Els[code];
#pragma unroll
                    for (int mi = 0; mi < 4; ++mi)
#pragma unroll
                        for (int r = 0; r < 4; ++r) {
                            float sv = fmaf(-2.f, acc[mi][ni][r], en);
                            if (sv < m1[mi][r]) { m2[mi][r] = m1[mi][r]; m1[mi][r] = sv; i1[mi][r] = code; }
                            else m2[mi][r] = fminf(m2[mi][r], sv);
                        }
                }
            }
        }
    }

    // butterfly across the 16 column-lanes (lex-min on (val, idx), keep min2)
#pragma unroll
    for (int mi = 0; mi < 4; ++mi)
#pragma unroll
        for (int r = 0; r < 4; ++r) {
            float a1 = m1[mi][r], a2 = m2[mi][r]; int ai = i1[mi][r];
#pragma unroll
            for (int m = 8; m >= 1; m >>= 1) {
                float b1 = __shfl_xor(a1, m, 64);
                float b2 = __shfl_xor(a2, m, 64);
                int   bi = __shfl_xor(ai, m, 64);
                bool take = (b1 < a1) || (b1 == a1 && bi < ai);
                float hi = take ? a1 : b1;
                a1 = take ? b1 : a1;
                ai = take ? bi : ai;
                a2 = fminf(fminf(a2, b2), hi);
            }
            m1[mi][r] = a1; m2[mi][r] = a2; i1[mi][r] = ai;
        }

    __syncthreads();                             // done with A/B/enorm; reuse LDS
    float* Lm1 = reinterpret_cast<float*>(lds);  // [2][128]
    float* Lm2 = Lm1 + 256;
    int*   Li1 = reinterpret_cast<int*>(Lm2 + 256);
    int*   Lidx = reinterpret_cast<int*>(lds + 3072);  // final idx per position
    if (l15 == 0) {
#pragma unroll
        for (int mi = 0; mi < 4; ++mi)
#pragma unroll
            for (int r = 0; r < 4; ++r) {
                int pos = wm * 64 + mi * 16 + l4 * 4 + r;
                Lm1[wn * 128 + pos] = m1[mi][r];
                Lm2[wn * 128 + pos] = m2[mi][r];
                Li1[wn * 128 + pos] = i1[mi][r];
            }
    }
    __syncthreads();
    if (t < 128) {
        float a1 = Lm1[t], a2 = Lm2[t]; int ai = Li1[t];
        float b1 = Lm1[128 + t], b2 = Lm2[128 + t]; int bi = Li1[128 + t];
        bool take = (b1 < a1) || (b1 == a1 && bi < ai);
        float hi = take ? a1 : b1;
        float f1 = take ? b1 : a1;
        int   fi = take ? bi : ai;
        float f2 = fminf(fminf(a2, b2), hi);
        int n = n0 + t;
        indf[n] = (float)fi;
        if (f2 - f1 < TAU) {                     // near-tie: exact rescan later
            int slot = atomicAdd(count, 1);
            list[slot] = n;
        }
        Lidx[t] = fi;
    }
    __syncthreads();

    // ---- fused gather epilogue: write this block's quantize columns.
    // Thread map: lanes t -> (dsub=t>>5, hoff=(t>>4)&1, w4=(t&15)*4);
    // lanes 0..31 write 512 B contiguous (two h rows of one d).
    {
        const int hoff = (t >> 4) & 1;
        const int w4   = (t & 15) * 4;
        const int dsub = t >> 5;
        const int li = hoff * 64 + w4;
        const int k0 = Lidx[li], k1 = Lidx[li + 1], k2 = Lidx[li + 2], k3 = Lidx[li + 3];
#pragma unroll 4
        for (int iter = 0; iter < 32; ++iter) {
            const int d = iter * 8 + dsub;
            const float* erow = embed + (size_t)d * K_CODES;
            float4 q;
            q.x = erow[k0]; q.y = erow[k1]; q.z = erow[k2]; q.w = erow[k3];
            if (b != 0 || d >= SKIPD) {
                size_t o = (((size_t)(b * 256 + d) * 64) + h0 + hoff) * 64 + w4;
                *reinterpret_cast<float4*>(out0 + o) = q;
                *reinterpret_cast<float4*>(out1 + o) = q;
            }
        }
    }
}

// ---------------------------------------------------------------------------
// Kernel 3: exact fp32 rescan — 8 flagged positions per wave; now also
// patches the output columns for refined positions (skip scratch region).
// ---------------------------------------------------------------------------
__launch_bounds__(256, 2)
__global__ void vq_refine(const float* __restrict__ input,
                          const float* __restrict__ embed,
                          const float* __restrict__ enorm,
                          float* __restrict__ indf,
                          float* __restrict__ out0,
                          float* __restrict__ out1,
                          const int* __restrict__ count,
                          const int* __restrict__ list) {
    __shared__ float xls[4][8][D_DIM];
    const int wslot = threadIdx.x >> 6;
    const int lane  = threadIdx.x & 63;
    const int gw    = blockIdx.x * 4 + wslot;
    const int nw    = gridDim.x * 4;
    const int cnt   = *count;
    if (cnt == 0) return;
    const int ngroups = (cnt + 7) >> 3;

    const float* ep = embed + lane * 16;
    float en[16];
    {
        float4 e0 = *reinterpret_cast<const float4*>(enorm + lane * 16);
        float4 e1 = *reinterpret_cast<const float4*>(enorm + lane * 16 + 4);
        float4 e2 = *reinterpret_cast<const float4*>(enorm + lane * 16 + 8);
        float4 e3 = *reinterpret_cast<const float4*>(enorm + lane * 16 + 12);
        en[0]=e0.x; en[1]=e0.y; en[2]=e0.z; en[3]=e0.w;
        en[4]=e1.x; en[5]=e1.y; en[6]=e1.z; en[7]=e1.w;
        en[8]=e2.x; en[9]=e2.y; en[10]=e2.z; en[11]=e2.w;
        en[12]=e3.x; en[13]=e3.y; en[14]=e3.z; en[15]=e3.w;
    }

    for (int g = gw; g < ngroups; g += nw) {
        int np[8];
        const float* bp[8];
#pragma unroll
        for (int p = 0; p < 8; ++p) {
            int li = g * 8 + p; if (li >= cnt) li = cnt - 1;   // tail dup: benign
            np[p] = list[li];
            int b = np[p] >> 12, rem = np[p] & 4095;
            bp[p] = input + (size_t)b * (D_DIM * HW) + rem;
        }
        // cooperative x-load: 32 independent strided lines per lane
#pragma unroll
        for (int j = 0; j < 32; ++j) {
            int p = j >> 2;
            int d = (j & 3) * 64 + lane;
            xls[wslot][p][d] = bp[p][(size_t)d * HW];
        }
        asm volatile("s_waitcnt lgkmcnt(0)" ::: "memory");
        __builtin_amdgcn_sched_barrier(0);

        float acc[8][16];
#pragma unroll
        for (int p = 0; p < 8; ++p)
#pragma unroll
            for (int j = 0; j < 16; ++j) acc[p][j] = 0.f;

        for (int d = 0; d < D_DIM; ++d) {
            const float* er = ep + (size_t)d * K_CODES;
            float4 e0 = *reinterpret_cast<const float4*>(er);
            float4 e1 = *reinterpret_cast<const float4*>(er + 4);
            float4 e2 = *reinterpret_cast<const float4*>(er + 8);
            float4 e3 = *reinterpret_cast<const float4*>(er + 12);
            float ea[16] = {e0.x, e0.y, e0.z, e0.w, e1.x, e1.y, e1.z, e1.w,
                            e2.x, e2.y, e2.z, e2.w, e3.x, e3.y, e3.z, e3.w};
#pragma unroll
            for (int p = 0; p < 8; ++p) {
                float xd = xls[wslot][p][d];
#pragma unroll
                for (int j = 0; j < 16; ++j)
                    acc[p][j] = fmaf(xd, ea[j], acc[p][j]);
            }
        }

#pragma unroll
        for (int p = 0; p < 8; ++p) {
            float bs = 3.402823466e38f; int bk = 0;
#pragma unroll
            for (int j = 0; j < 16; ++j) {
                float s = fmaf(-2.f, acc[p][j], en[j]);
                if (s < bs) { bs = s; bk = lane * 16 + j; }
            }
#pragma unroll
            for (int m = 32; m >= 1; m >>= 1) {
                float os = __shfl_xor(bs, m, 64);
                int   ok = __shfl_xor(bk, m, 64);
                if (os < bs || (os == bs && ok < bk)) { bs = os; bk = ok; }
            }
            // all lanes now hold the final (bs,bk) for position np[p]
            if (lane == 0) indf[np[p]] = (float)bk;
            // patch output columns (argmin wrote approx-index values there)
            const int b_ = np[p] >> 12, rem = np[p] & 4095;
            const int h_ = rem >> 6, w_ = rem & 63;
#pragma unroll
            for (int j = 0; j < 4; ++j) {
                int d = j * 64 + lane;
                float val = embed[(size_t)d * K_CODES + bk];
                if (b_ != 0 || d >= SKIPD) {
                    size_t o = (((size_t)(b_ * 256 + d) * 64) + h_) * 64 + w_;
                    out0[o] = val;
                    out1[o] = val;
                }
            }
        }
    }
}

// ---------------------------------------------------------------------------
// Kernel 4: cleanup — fill the b==0,d<SKIPD region (hosted scratch) of both
// outputs from the now-final indf. 132 blocks, ~1.1 MB writes.
// ---------------------------------------------------------------------------
__global__ void vq_cleanup(const float* __restrict__ embed,
                           const float* __restrict__ indf,
                           float* __restrict__ out0,
                           float* __restrict__ out1) {
    int gid  = blockIdx.x * 256 + threadIdx.x;   // 33*4096/4 = 33792 threads
    int idx4 = gid * 4;                          // b==0 flat float index
    int d  = idx4 >> 12;
    int hw = idx4 & 4095;                        // = h*64+w = position n (b=0)
    float4 fi = *reinterpret_cast<const float4*>(indf + hw);
    const float* erow = embed + (size_t)d * K_CODES;
    float4 q;
    q.x = erow[(int)fi.x];
    q.y = erow[(int)fi.y];
    q.z = erow[(int)fi.z];
    q.w = erow[(int)fi.w];
    *reinterpret_cast<float4*>(out0 + idx4) = q;
    *reinterpret_cast<float4*>(out1 + idx4) = q;
}

// ---------------------------------------------------------------------------
extern "C" void kernel_launch(void* const* d_in, const int* in_sizes, int n_in,
                              void* d_out, int out_size, void* d_ws, size_t ws_size,
                              hipStream_t stream) {
    const float* input = (const float*)d_in[0];  // [32, 256, 64, 64] f32
    const float* embed = (const float*)d_in[1];  // [256, 1024] f32
    float* out0 = (float*)d_out;
    float* out1 = out0 + (size_t)BDHW;
    float* indf = out0 + (size_t)2 * BDHW;

    // scratch inside d_out heads (b==0,d<SKIPD region; vq_cleanup rewrites it):
    uint4* embT  = (uint4*)out0;                 // 512 KB pre-swizzled f16 chunks
    float* enorm = out0 + 131072;                // 4 KB (right after embT)
    int* count = (int*)out1;
    int* list  = (int*)out1 + 1;

    vq_prep   <<<64,          256, 0, stream>>>(embed, embT);
    vq_enorm  <<<8,           256, 0, stream>>>(embed, enorm, count);
    vq_argmin <<<N_POS / 128, 256, 0, stream>>>(input, (const char*)embT, embed,
                                                enorm, indf, out0, out1, count, list);
    vq_refine <<<256,         256, 0, stream>>>(input, embed, enorm, indf,
                                                out0, out1, count, list);
    vq_cleanup<<<132,         256, 0, stream>>>(embed, indf, out0, out1);
}

// Round 11
// 270.324 us; speedup vs baseline: 1.2142x; 1.2142x over previous
//
#include <hip/hip_runtime.h>

#define D_DIM 256
#define K_CODES 1024
#define HW 4096                  // H*W
#define BDHW 33554432            // 32*256*64*64
#define N_POS 131072             // 32*64*64
#define TAU 0.25f                // ~11 sigma of f16 pair-error

typedef __attribute__((ext_vector_type(8))) _Float16 half8v;
typedef __attribute__((ext_vector_type(4))) float float4v;

__device__ __forceinline__ void load_lds16(const void* g, void* l) {
    __builtin_amdgcn_global_load_lds(
        (const __attribute__((address_space(1))) unsigned int*)g,
        (__attribute__((address_space(3))) unsigned int*)l, 16, 0, 0);
}

// ---------------------------------------------------------------------------
// Kernel 1 (fused): pre-swizzled f16 embT chunks + enorm + count=0.
// 64 blocks; blocks with dc==0 additionally compute enorm for their k-range.
// embT chunk (nc,dc), 8 KB: byte(r,sp)=r*64+sp*16 holds
// embed[dc*32 + (sp ^ ((r>>1)&3))*8 + j][nc*128 + r], j=0..7.
// ---------------------------------------------------------------------------
__global__ void vq_prep(const float* __restrict__ embed, uint4* __restrict__ embT,
                        float* __restrict__ enorm, int* __restrict__ count) {
    __shared__ float part[256];
    const int c  = blockIdx.x;                   // 64 chunks
    const int nc = c >> 3, dc = c & 7;
    const int t  = threadIdx.x;
#pragma unroll
    for (int i = 0; i < 2; ++i) {
        int p  = i * 256 + t;                    // piece 0..511 (16B each)
        int r  = p >> 2, sp = p & 3;
        int s  = sp ^ ((r >> 1) & 3);
        int k  = nc * 128 + r;
        int db = dc * 32 + s * 8;
        union { _Float16 h[8]; uint4 u; } pk;
#pragma unroll
        for (int j = 0; j < 8; ++j)
            pk.h[j] = (_Float16)embed[(size_t)(db + j) * K_CODES + k];
        embT[c * 512 + p] = pk.u;
    }
    if (dc == 0) {
        const int k = nc * 128 + (t & 127);
        const int hf = t >> 7;
        float s = 0.f;
#pragma unroll 4
        for (int d = hf * 128; d < hf * 128 + 128; ++d) {
            float e = embed[(size_t)d * K_CODES + k];
            s = fmaf(e, e, s);
        }
        part[t] = s;
        __syncthreads();
        if (t < 128) enorm[k] = part[t] + part[t + 128];
        if (c == 0 && t == 0) *count = 0;
    }
}

// ---------------------------------------------------------------------------
// Kernel 2: f16 MFMA distances + argmin — BYTE-IDENTICAL to the 251-us
// round-6 version (ring-4 8KB, stage-ahead-2, vmcnt(4), aR[4][4] d<128,
// A-LDS 32KB d>=128, 1 barrier/step).
// ---------------------------------------------------------------------------
__launch_bounds__(256, 2)
__global__ void vq_argmin(const float* __restrict__ input,
                          const char* __restrict__ embT,
                          const float* __restrict__ enorm,
                          float* __restrict__ indf,
                          int* __restrict__ count,
                          int* __restrict__ list) {
    __shared__ __align__(16) char lds[69632];
    char*  Als = lds;                            // 32 KB: row r<128 -> 256B, 16 slots, d=128+slot*8+j
    char*  Bls = lds + 32768;                    // 4 x 8 KB B ring
    float* Els = (float*)(lds + 65536);          // 4 KB enorm

    const int t    = threadIdx.x;
    const int lane = t & 63;
    const int wid  = t >> 6;
    const int blk  = blockIdx.x;                 // 1024 blocks
    const int n0   = blk * 128;
    const int b    = n0 >> 12;
    const int h0   = (n0 & 4095) >> 6;           // rows h0, h0+1
    const int wm = wid >> 1, wn = wid & 1;
    const int l15 = lane & 15, l4 = lane >> 4;

    const char* embTw = embT + wid * 2048 + lane * 16;   // per-wave stage base

    // ---- prologue: stage chunks 0,1 into ring slots 0,1
    load_lds16(embTw,                   Bls + wid * 2048);
    load_lds16(embTw + 1024,            Bls + wid * 2048 + 1024);
    load_lds16(embTw + 8192,            Bls + 8192 + wid * 2048);
    load_lds16(embTw + 8192 + 1024,     Bls + 8192 + wid * 2048 + 1024);

    // ---- stage enorm to LDS
    *reinterpret_cast<float4*>(Els + t * 4) =
        *reinterpret_cast<const float4*>(enorm + t * 4);

    // ---- stage A d in [128,256) to LDS (coalesced dword loads, b128 writes)
    const float* xbase = input + (size_t)b * (D_DIM * HW) + h0 * 64;
#pragma unroll
    for (int half = 0; half < 2; ++half) {
        const int r = half * 64 + lane;
        const float* hp = xbase + half * 64 + lane;
        const int r7 = lane & 7;
#pragma unroll
        for (int q = 0; q < 4; ++q) {
            const int slot = wid * 4 + q;         // 0..15
            const int d = 128 + slot * 8;
            float v[8];
#pragma unroll
            for (int j = 0; j < 8; ++j) v[j] = hp[(size_t)(d + j) * HW];
            union { _Float16 h[8]; uint4 u; } pk;
#pragma unroll
            for (int j = 0; j < 8; ++j) pk.h[j] = (_Float16)v[j];
            const int byte = r * 256 + (((slot & 8) | ((slot & 7) ^ r7)) << 4);
            *reinterpret_cast<uint4*>(Als + byte) = pk.u;
        }
    }

    // ---- A d<128 directly global -> registers (this wave's 64 pos)
    half8v aR[4][4];                             // [mi][dcq], d = dcq*32 + l4*8 + j
    {
        const float* xw = xbase + wm * 64;
#pragma unroll
        for (int dcq = 0; dcq < 4; ++dcq)
#pragma unroll
            for (int mi = 0; mi < 4; ++mi) {
                const float* p = xw + (size_t)(dcq * 32 + l4 * 8) * HW + mi * 16 + l15;
                float v[8];
#pragma unroll
                for (int j = 0; j < 8; ++j) v[j] = p[(size_t)j * HW];
                union { _Float16 h[8]; half8v hv; } pk;
#pragma unroll
                for (int j = 0; j < 8; ++j) pk.h[j] = (_Float16)v[j];
                aR[mi][dcq] = pk.hv;
            }
    }

    asm volatile("s_waitcnt vmcnt(0) lgkmcnt(0)" ::: "memory");
    __builtin_amdgcn_s_barrier();
    __builtin_amdgcn_sched_barrier(0);

    // fragment base addresses
    const int r7a = l15 & 7;
    const int A0 = (wm * 64 + l15) * 256;                      // + mi*4096 + swz
    const int B0 = wn * 4096 + l15 * 64 + ((l4 ^ ((l15 >> 1) & 3)) << 4); // + ni*1024

    float m1[4][4], m2[4][4];
    int   i1[4][4];
#pragma unroll
    for (int mi = 0; mi < 4; ++mi)
#pragma unroll
        for (int r = 0; r < 4; ++r) { m1[mi][r] = 3.402823466e38f; m2[mi][r] = 3.402823466e38f; i1[mi][r] = 0; }

    float4v acc[4][4];

    for (int ss = 0; ss < 8; ++ss) {             // 8 nc chunks of 128 codes
#pragma unroll
        for (int dc = 0; dc < 8; ++dc) {         // K=32 steps (compile-time dc)
            const int s = ss * 8 + dc;
            // 1. stage chunk s+2 into ring slot (dc+2)&3
            if (ss < 7 || dc < 6) {
                const char* src = embTw + (size_t)(s + 2) * 8192;
                char* dst = Bls + ((dc + 2) & 3) * 8192 + wid * 2048;
                load_lds16(src, dst);
                load_lds16(src + 1024, dst + 1024);
            }
            // 2. counted wait
            if (ss < 7 || dc < 6)  asm volatile("s_waitcnt vmcnt(4)" ::: "memory");
            else if (dc == 6)      asm volatile("s_waitcnt vmcnt(2)" ::: "memory");
            else                   asm volatile("s_waitcnt vmcnt(0)" ::: "memory");
            // 3. one barrier per step
            __builtin_amdgcn_s_barrier();
            __builtin_amdgcn_sched_barrier(0);
            // 4. zero acc at chunk start
            if (dc == 0) {
#pragma unroll
                for (int mi = 0; mi < 4; ++mi)
#pragma unroll
                    for (int ni = 0; ni < 4; ++ni) acc[mi][ni] = (float4v){0.f, 0.f, 0.f, 0.f};
            }
            // 5. fragments
            const char* curB = Bls + (dc & 3) * 8192;
            half8v bF[4], aU[4];
#pragma unroll
            for (int ni = 0; ni < 4; ++ni)
                bF[ni] = *reinterpret_cast<const half8v*>(curB + B0 + ni * 1024);
            if (dc < 4) {
#pragma unroll
                for (int mi = 0; mi < 4; ++mi) aU[mi] = aR[mi][dc];
            } else {
                const int slot = (dc - 4) * 4 + l4;
                const int swz = ((slot & 8) | ((slot & 7) ^ r7a)) << 4;
#pragma unroll
                for (int mi = 0; mi < 4; ++mi)
                    aU[mi] = *reinterpret_cast<const half8v*>(Als + A0 + mi * 4096 + swz);
            }
            // 6. MFMA
            __builtin_amdgcn_s_setprio(1);
#pragma unroll
            for (int mi = 0; mi < 4; ++mi)
#pragma unroll
                for (int ni = 0; ni < 4; ++ni)
                    acc[mi][ni] = __builtin_amdgcn_mfma_f32_16x16x32_f16(aU[mi], bF[ni], acc[mi][ni], 0, 0, 0);
            __builtin_amdgcn_s_setprio(0);
            // 7. epilogue per 128-code chunk
            if (dc == 7) {
#pragma unroll
                for (int ni = 0; ni < 4; ++ni) {
                    int code = ss * 128 + wn * 64 + ni * 16 + l15;
                    float en = Els[code];
#pragma unroll
                    for (int mi = 0; mi < 4; ++mi)
#pragma unroll
                        for (int r = 0; r < 4; ++r) {
                            float sv = fmaf(-2.f, acc[mi][ni][r], en);
                            if (sv < m1[mi][r]) { m2[mi][r] = m1[mi][r]; m1[mi][r] = sv; i1[mi][r] = code; }
                            else m2[mi][r] = fminf(m2[mi][r], sv);
                        }
                }
            }
        }
    }

    // butterfly across the 16 column-lanes (lex-min on (val, idx), keep min2)
#pragma unroll
    for (int mi = 0; mi < 4; ++mi)
#pragma unroll
        for (int r = 0; r < 4; ++r) {
            float a1 = m1[mi][r], a2 = m2[mi][r]; int ai = i1[mi][r];
#pragma unroll
            for (int m = 8; m >= 1; m >>= 1) {
                float b1 = __shfl_xor(a1, m, 64);
                float b2 = __shfl_xor(a2, m, 64);
                int   bi = __shfl_xor(ai, m, 64);
                bool take = (b1 < a1) || (b1 == a1 && bi < ai);
                float hi = take ? a1 : b1;
                a1 = take ? b1 : a1;
                ai = take ? bi : ai;
                a2 = fminf(fminf(a2, b2), hi);
            }
            m1[mi][r] = a1; m2[mi][r] = a2; i1[mi][r] = ai;
        }

    __syncthreads();                             // done with A/B/enorm; reuse LDS
    float* Lm1 = reinterpret_cast<float*>(lds);  // [2][128]
    float* Lm2 = Lm1 + 256;
    int*   Li1 = reinterpret_cast<int*>(Lm2 + 256);
    if (l15 == 0) {
#pragma unroll
        for (int mi = 0; mi < 4; ++mi)
#pragma unroll
            for (int r = 0; r < 4; ++r) {
                int pos = wm * 64 + mi * 16 + l4 * 4 + r;
                Lm1[wn * 128 + pos] = m1[mi][r];
                Lm2[wn * 128 + pos] = m2[mi][r];
                Li1[wn * 128 + pos] = i1[mi][r];
            }
    }
    __syncthreads();
    if (t < 128) {
        float a1 = Lm1[t], a2 = Lm2[t]; int ai = Li1[t];
        float b1 = Lm1[128 + t], b2 = Lm2[128 + t]; int bi = Li1[128 + t];
        bool take = (b1 < a1) || (b1 == a1 && bi < ai);
        float hi = take ? a1 : b1;
        float f1 = take ? b1 : a1;
        int   fi = take ? bi : ai;
        float f2 = fminf(fminf(a2, b2), hi);
        int n = n0 + t;
        indf[n] = (float)fi;
        if (f2 - f1 < TAU) {                     // near-tie: exact rescan later
            int slot = atomicAdd(count, 1);
            list[slot] = n;
        }
    }
}

// ---------------------------------------------------------------------------
// Kernel 3: exact fp32 rescan v4 — 8 positions per 128-thr block, K split
// across the 2 waves (wave0: codes 0-511, wave1: 512-1023), LDS combine.
// Per-code d-summation order identical to all prior passing versions.
// ---------------------------------------------------------------------------
__launch_bounds__(128, 4)
__global__ void vq_refine(const float* __restrict__ input,
                          const float* __restrict__ embed,
                          const float* __restrict__ enorm,
                          float* __restrict__ indf,
                          const int* __restrict__ count,
                          const int* __restrict__ list) {
    __shared__ float xls[8][D_DIM];
    __shared__ float sLs[2][8];
    __shared__ int   sLk[2][8];
    const int t    = threadIdx.x;                // 0..127
    const int wv   = t >> 6;
    const int lane = t & 63;
    const int cnt  = *count;
    if (cnt == 0) return;
    const int ngroups = (cnt + 7) >> 3;

    const int k0 = wv * 512 + lane * 8;          // this lane's 8 codes
    const float* ep = embed + k0;
    float en[8];
    {
        float4 e0 = *reinterpret_cast<const float4*>(enorm + k0);
        float4 e1 = *reinterpret_cast<const float4*>(enorm + k0 + 4);
        en[0]=e0.x; en[1]=e0.y; en[2]=e0.z; en[3]=e0.w;
        en[4]=e1.x; en[5]=e1.y; en[6]=e1.z; en[7]=e1.w;
    }

    for (int g = blockIdx.x; g < ngroups; g += gridDim.x) {
        __syncthreads();                         // xls/sL reuse safe
        // cooperative x-load: 16 loads/thread, coalesced across t per d
#pragma unroll
        for (int j = 0; j < 16; ++j) {
            const int p = j >> 1;
            const int d = (j & 1) * 128 + t;
            int li = g * 8 + p; if (li >= cnt) li = cnt - 1;   // tail dup: benign
            const int n = list[li];
            const int b = n >> 12, rem = n & 4095;
            xls[p][d] = input[(size_t)b * (D_DIM * HW) + (size_t)d * HW + rem];
        }
        __syncthreads();

        float acc[8][8];
#pragma unroll
        for (int p = 0; p < 8; ++p)
#pragma unroll
            for (int j = 0; j < 8; ++j) acc[p][j] = 0.f;

        for (int d = 0; d < D_DIM; ++d) {
            const float* er = ep + (size_t)d * K_CODES;
            float4 e0 = *reinterpret_cast<const float4*>(er);
            float4 e1 = *reinterpret_cast<const float4*>(er + 4);
            float ea[8] = {e0.x, e0.y, e0.z, e0.w, e1.x, e1.y, e1.z, e1.w};
#pragma unroll
            for (int p = 0; p < 8; ++p) {
                float xd = xls[p][d];
#pragma unroll
                for (int j = 0; j < 8; ++j)
                    acc[p][j] = fmaf(xd, ea[j], acc[p][j]);
            }
        }

#pragma unroll
        for (int p = 0; p < 8; ++p) {
            float bs = 3.402823466e38f; int bk = 0;
#pragma unroll
            for (int j = 0; j < 8; ++j) {
                float s = fmaf(-2.f, acc[p][j], en[j]);
                if (s < bs) { bs = s; bk = k0 + j; }
            }
#pragma unroll
            for (int m = 32; m >= 1; m >>= 1) {
                float os = __shfl_xor(bs, m, 64);
                int   ok = __shfl_xor(bk, m, 64);
                if (os < bs || (os == bs && ok < bk)) { bs = os; bk = ok; }
            }
            if (lane == 0) { sLs[wv][p] = bs; sLk[wv][p] = bk; }
        }
        __syncthreads();
        if (t < 8) {
            float a = sLs[0][t]; int ak = sLk[0][t];
            float c = sLs[1][t]; int ck = sLk[1][t];
            bool take = (c < a) || (c == a && ck < ak);
            int li = g * 8 + t; if (li >= cnt) li = cnt - 1;
            indf[list[li]] = (float)(take ? ck : ak);
        }
    }
}

// ---------------------------------------------------------------------------
// Kernel 4: gather outputs (overwrites the scratch regions last)
// ---------------------------------------------------------------------------
__global__ void vq_gather(const float* __restrict__ embed,
                          const float* __restrict__ indf,
                          float* __restrict__ out0,
                          float* __restrict__ out1) {
    int gid = blockIdx.x * 256 + threadIdx.x;    // BDHW/4 threads
    int w4   = (gid & 15) * 4;
    int rest = gid >> 4;
    int h  = rest & 63;
    int bd = rest >> 6;
    int d  = bd & 255;
    int b  = bd >> 8;
    int n  = (b * 64 + h) * 64 + w4;
    float4 fi = *reinterpret_cast<const float4*>(indf + n);
    const float* erow = embed + (size_t)d * K_CODES;
    float4 q;
    q.x = erow[(int)fi.x];
    q.y = erow[(int)fi.y];
    q.z = erow[(int)fi.z];
    q.w = erow[(int)fi.w];
    size_t o = (size_t)gid * 4;
    *reinterpret_cast<float4*>(out0 + o) = q;
    *reinterpret_cast<float4*>(out1 + o) = q;
}

// ---------------------------------------------------------------------------
extern "C" void kernel_launch(void* const* d_in, const int* in_sizes, int n_in,
                              void* d_out, int out_size, void* d_ws, size_t ws_size,
                              hipStream_t stream) {
    const float* input = (const float*)d_in[0];  // [32, 256, 64, 64] f32
    const float* embed = (const float*)d_in[1];  // [256, 1024] f32
    float* out0 = (float*)d_out;
    float* out1 = out0 + (size_t)BDHW;
    float* indf = out0 + (size_t)2 * BDHW;

    // scratch inside d_out (overwritten by vq_gather at the end):
    uint4* embT  = (uint4*)out0;                 // 512 KB pre-swizzled f16 chunks
    float* enorm = out0 + 131072;                // 4 KB (right after embT)
    int* count = (int*)out1;
    int* list  = (int*)out1 + 1;

    vq_prep  <<<64,          256, 0, stream>>>(embed, embT, enorm, count);
    vq_argmin<<<N_POS / 128, 256, 0, stream>>>(input, (const char*)embT, enorm, indf, count, list);
    vq_refine<<<512,         128, 0, stream>>>(input, embed, enorm, indf, count, list);
    vq_gather<<<BDHW / 1024, 256, 0, stream>>>(embed, indf, out0, out1);
}